// Round 1
// baseline (429.107 us; speedup 1.0000x reference)
//
#include <hip/hip_runtime.h>
#include <math.h>

// Problem constants (pred: (1,16,384,384) fp32, labels int32, area fp32[256])
constexpr int ZN = 16, YN = 384, XN = 384;
constexpr int NZ = 17, NY = 385, NX = 385;   // node grid (unfold output)
constexpr int NP = NY * NX;                  // 148225 nodes per z-slab
constexpr int TOTAL = NZ * NP;               // 2519825 nodes

__global__ __launch_bounds__(256) void sd_main(
        const float* __restrict__ pred,
        const int*   __restrict__ labels,
        const float* __restrict__ area,
        double*      __restrict__ acc)
{
    __shared__ float s_area[256];
    s_area[threadIdx.x] = area[threadIdx.x];
    __syncthreads();

    float num = 0.f, den = 0.f, vol = 0.f;
    const int stride = gridDim.x * blockDim.x;
    for (int i = blockIdx.x * blockDim.x + threadIdx.x; i < TOTAL; i += stride) {
        const int z   = i / NP;
        const int rem = i - z * NP;
        const int y   = rem / NX;
        const int x   = rem - y * NX;

        float pc[8];
        float lf[8];
        int byte = 0, pbyte = 0;
#pragma unroll
        for (int k = 0; k < 8; ++k) {
            const int dz = k >> 2, dy = (k >> 1) & 1, dx = k & 1;
            const int zz = z + dz - 1, yy = y + dy - 1, xx = x + dx - 1;
            const bool in = ((unsigned)zz < (unsigned)ZN) &
                            ((unsigned)yy < (unsigned)YN) &
                            ((unsigned)xx < (unsigned)XN);
            float p = 0.f; int l = 0;
            if (in) {
                const int off = (zz * YN + yy) * XN + xx;
                p = pred[off];
                l = labels[off];
            }
            // padding applied AFTER sigmoid in reference -> padded pc is exactly 0
            const float s = in ? __fdividef(1.f, 1.f + __expf(-p)) : 0.f;
            pc[k] = s;
            lf[k] = (float)l;
            byte  |= l << k;
            // argmax over 256 codes is bit-separable: bit k set iff pc_k > 0.5
            // (ties at exactly 0.5 -> bit 0, matching argmax-first semantics)
            pbyte |= (int)(in && (p > 0.f)) << k;
        }

        float sq = 0.f;
#pragma unroll
        for (int k = 0; k < 8; ++k) { const float d = pc[k] - lf[k]; sq += d * d; }
        const float pw = 1.f - sq * 0.125f;

        const float la = s_area[byte];
        const float pa = s_area[pbyte];
        num += 2.f * pw * la;
        den += la + pa;

        if (byte == 0 || byte == 255) {
            float b = 0.f;
#pragma unroll
            for (int k = 0; k < 8; ++k) {
                // lf is exactly 0 or 1, so BCE reduces to a select
                const float t = (lf[k] != 0.f) ? __logf(fmaxf(pc[k], 1e-12f))
                                               : __logf(fmaxf(1.f - pc[k], 1e-12f));
                b -= t;
            }
            vol += b;
        }
    }

    // wave64 shuffle reduction
#pragma unroll
    for (int off = 32; off > 0; off >>= 1) {
        num += __shfl_down(num, off);
        den += __shfl_down(den, off);
        vol += __shfl_down(vol, off);
    }
    __shared__ float sn[4], sd_[4], sv[4];
    const int lane = threadIdx.x & 63, w = threadIdx.x >> 6;
    if (lane == 0) { sn[w] = num; sd_[w] = den; sv[w] = vol; }
    __syncthreads();
    if (threadIdx.x == 0) {
        const float n = sn[0] + sn[1] + sn[2] + sn[3];
        const float d = sd_[0] + sd_[1] + sd_[2] + sd_[3];
        const float v = sv[0] + sv[1] + sv[2] + sv[3];
        atomicAdd(&acc[0], (double)n);
        atomicAdd(&acc[1], (double)d);
        atomicAdd(&acc[2], (double)v);
    }
}

__global__ void sd_final(const double* __restrict__ acc, float* __restrict__ out)
{
    const double num = acc[0];
    const double den = acc[1];
    const double vol = acc[2] / (8.0 * (double)NP);
    const double dice = 1.0 - (num + 1e-3) / (den + 1e-3);
    out[0] = (float)(dice + vol);
}

extern "C" void kernel_launch(void* const* d_in, const int* in_sizes, int n_in,
                              void* d_out, int out_size, void* d_ws, size_t ws_size,
                              hipStream_t stream)
{
    const float* pred   = (const float*)d_in[0];
    const int*   labels = (const int*)d_in[1];
    const float* area   = (const float*)d_in[2];
    float*  out = (float*)d_out;
    double* acc = (double*)d_ws;

    hipMemsetAsync(acc, 0, 3 * sizeof(double), stream);

    const int threads = 256;
    const int blocks  = (TOTAL + threads - 1) / threads;  // 9844
    sd_main<<<blocks, threads, 0, stream>>>(pred, labels, area, acc);
    sd_final<<<1, 1, 0, stream>>>(acc, out);
}

// Round 2
// 99.596 us; speedup vs baseline: 4.3085x; 4.3085x over previous
//
#include <hip/hip_runtime.h>
#include <math.h>

// Problem constants (pred: (1,16,384,384) fp32, labels int32, area fp32[256])
constexpr int ZN = 16, YN = 384, XN = 384;
constexpr int NZ = 17, NY = 385, NX = 385;   // node grid (unfold output)
constexpr int NP = NY * NX;                  // 148225 nodes per z-slab
constexpr int TOTAL = NZ * NP;               // 2519825 nodes

constexpr int NBLK = 1280;                   // 5 blocks/CU @ 256 thr -> full occupancy

__global__ __launch_bounds__(256) void sd_main(
        const float* __restrict__ pred,
        const int*   __restrict__ labels,
        const float* __restrict__ area,
        float*       __restrict__ partial)   // [3 * NBLK]: num | den | vol
{
    __shared__ float s_area[256];
    s_area[threadIdx.x] = area[threadIdx.x];
    __syncthreads();

    float num = 0.f, den = 0.f, vol = 0.f;
    const int stride = gridDim.x * blockDim.x;
    for (int i = blockIdx.x * blockDim.x + threadIdx.x; i < TOTAL; i += stride) {
        const int z   = i / NP;
        const int rem = i - z * NP;
        const int y   = rem / NX;
        const int x   = rem - y * NX;

        float pc[8];
        float lf[8];
        int byte = 0, pbyte = 0;
#pragma unroll
        for (int k = 0; k < 8; ++k) {
            const int dz = k >> 2, dy = (k >> 1) & 1, dx = k & 1;
            const int zz = z + dz - 1, yy = y + dy - 1, xx = x + dx - 1;
            const bool in = ((unsigned)zz < (unsigned)ZN) &
                            ((unsigned)yy < (unsigned)YN) &
                            ((unsigned)xx < (unsigned)XN);
            float p = 0.f; int l = 0;
            if (in) {
                const int off = (zz * YN + yy) * XN + xx;
                p = pred[off];
                l = labels[off];
            }
            // padding applied AFTER sigmoid in reference -> padded pc is exactly 0
            const float s = in ? __fdividef(1.f, 1.f + __expf(-p)) : 0.f;
            pc[k] = s;
            lf[k] = (float)l;
            byte  |= l << k;
            // argmax over 256 codes is bit-separable: bit k set iff pc_k > 0.5
            // (ties at exactly 0.5 -> bit 0, matching argmax-first semantics)
            pbyte |= (int)(in && (p > 0.f)) << k;
        }

        float sq = 0.f;
#pragma unroll
        for (int k = 0; k < 8; ++k) { const float d = pc[k] - lf[k]; sq += d * d; }
        const float pw = 1.f - sq * 0.125f;

        const float la = s_area[byte];
        const float pa = s_area[pbyte];
        num += 2.f * pw * la;
        den += la + pa;

        if (byte == 0 || byte == 255) {
            float b = 0.f;
#pragma unroll
            for (int k = 0; k < 8; ++k) {
                // lf is exactly 0 or 1, so BCE reduces to a select
                const float t = (lf[k] != 0.f) ? __logf(fmaxf(pc[k], 1e-12f))
                                               : __logf(fmaxf(1.f - pc[k], 1e-12f));
                b -= t;
            }
            vol += b;
        }
    }

    // wave64 shuffle reduction
#pragma unroll
    for (int off = 32; off > 0; off >>= 1) {
        num += __shfl_down(num, off);
        den += __shfl_down(den, off);
        vol += __shfl_down(vol, off);
    }
    __shared__ float sn[4], sd_[4], sv[4];
    const int lane = threadIdx.x & 63, w = threadIdx.x >> 6;
    if (lane == 0) { sn[w] = num; sd_[w] = den; sv[w] = vol; }
    __syncthreads();
    if (threadIdx.x == 0) {
        partial[blockIdx.x]            = sn[0] + sn[1] + sn[2] + sn[3];
        partial[NBLK + blockIdx.x]     = sd_[0] + sd_[1] + sd_[2] + sd_[3];
        partial[2 * NBLK + blockIdx.x] = sv[0] + sv[1] + sv[2] + sv[3];
    }
}

__global__ __launch_bounds__(256) void sd_final(
        const float* __restrict__ partial, float* __restrict__ out)
{
    double n = 0.0, d = 0.0, v = 0.0;
    for (int b = threadIdx.x; b < NBLK; b += 256) {
        n += (double)partial[b];
        d += (double)partial[NBLK + b];
        v += (double)partial[2 * NBLK + b];
    }
#pragma unroll
    for (int off = 32; off > 0; off >>= 1) {
        n += __shfl_down(n, off);
        d += __shfl_down(d, off);
        v += __shfl_down(v, off);
    }
    __shared__ double sn[4], sd_[4], sv[4];
    const int lane = threadIdx.x & 63, w = threadIdx.x >> 6;
    if (lane == 0) { sn[w] = n; sd_[w] = d; sv[w] = v; }
    __syncthreads();
    if (threadIdx.x == 0) {
        const double num = sn[0] + sn[1] + sn[2] + sn[3];
        const double den = sd_[0] + sd_[1] + sd_[2] + sd_[3];
        const double vol = (sv[0] + sv[1] + sv[2] + sv[3]) / (8.0 * (double)NP);
        const double dice = 1.0 - (num + 1e-3) / (den + 1e-3);
        out[0] = (float)(dice + vol);
    }
}

extern "C" void kernel_launch(void* const* d_in, const int* in_sizes, int n_in,
                              void* d_out, int out_size, void* d_ws, size_t ws_size,
                              hipStream_t stream)
{
    const float* pred   = (const float*)d_in[0];
    const int*   labels = (const int*)d_in[1];
    const float* area   = (const float*)d_in[2];
    float* out     = (float*)d_out;
    float* partial = (float*)d_ws;   // 3*NBLK floats, fully overwritten each call

    sd_main<<<NBLK, 256, 0, stream>>>(pred, labels, area, partial);
    sd_final<<<1, 256, 0, stream>>>(partial, out);
}

// Round 3
// 89.074 us; speedup vs baseline: 4.8174x; 1.1181x over previous
//
#include <hip/hip_runtime.h>
#include <math.h>

// pred: (1,16,384,384) fp32, labels int32 same shape, area fp32[256]
constexpr int ZN = 16, YN = 384, XN = 384;
constexpr int NZ = 17, NY = 385, NX = 385;   // node grid
constexpr int NP = NY * NX;                  // 148225 nodes per z-slab
constexpr int NROWS = NZ * NY;               // 6545 node rows
constexpr int BLOCKS = 1637;                 // 4 waves/block -> 6548 waves, 1 row each

__global__ __launch_bounds__(256) void sd_main(
        const float* __restrict__ pred,
        const int*   __restrict__ labels,
        const float* __restrict__ area,
        float*       __restrict__ partial)   // [3 * BLOCKS]
{
    // Re-indexed LUT: idx = (own_label_bits << 4) | prev_label_bits,
    // where corner k = 2r+dx, r = 2dz+dy; dx=1 -> own column, dx=0 -> prev.
    __shared__ float s_area[256];
    {
        const int t = threadIdx.x;
        const int own = t >> 4, prv = t & 15;
        int code = 0;
#pragma unroll
        for (int r = 0; r < 4; ++r)
            code |= (((prv >> r) & 1) << (2 * r)) | (((own >> r) & 1) << (2 * r + 1));
        s_area[t] = area[code];
    }
    __syncthreads();

    const int lane = threadIdx.x & 63;
    const int wid  = blockIdx.x * 4 + (threadIdx.x >> 6);

    float num = 0.f, den = 0.f, vol = 0.f;

    if (wid < NROWS) {
        const int z = wid / NY;          // 0..16
        const int y = wid - z * NY;      // 0..384

        bool rv[4]; int base[4];
#pragma unroll
        for (int r = 0; r < 4; ++r) {
            const int zz = z - 1 + (r >> 1);
            const int yy = y - 1 + (r & 1);
            rv[r]   = ((unsigned)zz < (unsigned)ZN) & ((unsigned)yy < (unsigned)YN);
            base[r] = (zz * YN + yy) * XN;
        }

        float cs[4] = {0.f, 0.f, 0.f, 0.f};   // lane63 sigmoid carry
        int   cb = 0;                          // lane63 packed-bits carry

        auto do_node = [&](const float s[4], int LP, const float ps[4], int PLP) {
            const int idxL = ((LP & 15) << 4) | (PLP & 15);
            const int idxP = (LP & 0xF0) | (PLP >> 4);
            const float la = s_area[idxL];
            const float pa = s_area[idxP];
            float u[8];
            float sq = 0.f;
#pragma unroll
            for (int r = 0; r < 4; ++r) {
                // u = probability assigned to the true label; (pc-lf)^2 = (1-u)^2
                const float u0 = ((PLP >> r) & 1) ? ps[r] : 1.f - ps[r];
                const float u1 = ((LP  >> r) & 1) ? s[r]  : 1.f - s[r];
                u[2 * r] = u0; u[2 * r + 1] = u1;
                const float d0 = 1.f - u0, d1 = 1.f - u1;
                sq += d0 * d0 + d1 * d1;
            }
            const float pw = 1.f - sq * 0.125f;
            num += 2.f * pw * la;
            den += la + pa;
            if (idxL == 0 || idxL == 255) {   // interior (byte==0 or 255), ~0.8% of nodes
                float b = 0.f;
#pragma unroll
                for (int k = 0; k < 8; ++k)
                    b += __logf(fmaxf(u[k], 1e-12f));
                vol -= b;
            }
        };

        for (int chunk = 0; chunk < 6; ++chunk) {
            const int x = chunk * 64 + lane;        // node x; own voxel column = x (0..383, always valid)
            float s[4]; int LP = 0;
#pragma unroll
            for (int r = 0; r < 4; ++r) {
                if (rv[r]) {
                    const float p = pred[base[r] + x];
                    const int   l = labels[base[r] + x];
                    s[r] = __fdividef(1.f, 1.f + __expf(-p));  // sigmoid, once per voxel-column entry
                    LP  |= (l << r) | ((int)(p > 0.f) << (r + 4));
                } else {
                    s[r] = 0.f;                      // pad applied AFTER sigmoid -> exactly 0
                }
            }
            // previous column from lane-1 (lane 0: carry from previous chunk / x=-1 pad)
            float ps[4]; int PLP;
#pragma unroll
            for (int r = 0; r < 4; ++r) ps[r] = __shfl_up(s[r], 1);
            PLP = __shfl_up(LP, 1);
            if (lane == 0) {
#pragma unroll
                for (int r = 0; r < 4; ++r) ps[r] = cs[r];
                PLP = cb;
            }
            do_node(s, LP, ps, PLP);
#pragma unroll
            for (int r = 0; r < 4; ++r) cs[r] = __shfl(s[r], 63);
            cb = __shfl(LP, 63);
        }
        // final node x = 384: own column entirely padding (pc=0, bits=0)
        if (lane == 0) {
            const float zs[4] = {0.f, 0.f, 0.f, 0.f};
            do_node(zs, 0, cs, cb);
        }
    }

    // block reduction
#pragma unroll
    for (int off = 32; off > 0; off >>= 1) {
        num += __shfl_down(num, off);
        den += __shfl_down(den, off);
        vol += __shfl_down(vol, off);
    }
    __shared__ float sn[4], sd_[4], sv[4];
    const int w = threadIdx.x >> 6;
    if (lane == 0) { sn[w] = num; sd_[w] = den; sv[w] = vol; }
    __syncthreads();
    if (threadIdx.x == 0) {
        partial[blockIdx.x]              = sn[0] + sn[1] + sn[2] + sn[3];
        partial[BLOCKS + blockIdx.x]     = sd_[0] + sd_[1] + sd_[2] + sd_[3];
        partial[2 * BLOCKS + blockIdx.x] = sv[0] + sv[1] + sv[2] + sv[3];
    }
}

__global__ __launch_bounds__(256) void sd_final(
        const float* __restrict__ partial, float* __restrict__ out)
{
    double n = 0.0, d = 0.0, v = 0.0;
    for (int b = threadIdx.x; b < BLOCKS; b += 256) {
        n += (double)partial[b];
        d += (double)partial[BLOCKS + b];
        v += (double)partial[2 * BLOCKS + b];
    }
#pragma unroll
    for (int off = 32; off > 0; off >>= 1) {
        n += __shfl_down(n, off);
        d += __shfl_down(d, off);
        v += __shfl_down(v, off);
    }
    __shared__ double sn[4], sd_[4], sv[4];
    const int lane = threadIdx.x & 63, w = threadIdx.x >> 6;
    if (lane == 0) { sn[w] = n; sd_[w] = d; sv[w] = v; }
    __syncthreads();
    if (threadIdx.x == 0) {
        const double num = sn[0] + sn[1] + sn[2] + sn[3];
        const double den = sd_[0] + sd_[1] + sd_[2] + sd_[3];
        const double vol = (sv[0] + sv[1] + sv[2] + sv[3]) / (8.0 * (double)NP);
        const double dice = 1.0 - (num + 1e-3) / (den + 1e-3);
        out[0] = (float)(dice + vol);
    }
}

extern "C" void kernel_launch(void* const* d_in, const int* in_sizes, int n_in,
                              void* d_out, int out_size, void* d_ws, size_t ws_size,
                              hipStream_t stream)
{
    const float* pred   = (const float*)d_in[0];
    const int*   labels = (const int*)d_in[1];
    const float* area   = (const float*)d_in[2];
    float* out     = (float*)d_out;
    float* partial = (float*)d_ws;   // 3*BLOCKS floats, fully overwritten each call

    sd_main<<<BLOCKS, 256, 0, stream>>>(pred, labels, area, partial);
    sd_final<<<1, 256, 0, stream>>>(partial, out);
}